// Round 4
// baseline (524.573 us; speedup 1.0000x reference)
//
#include <hip/hip_runtime.h>
#include <math.h>

#define HW   2816           // 32*88
#define IMGS 6
#define DD   59
#define NV   16384          // 128*128 BEV cells (B=1)
#define COUT 128
#define NPIX (IMGS*HW)      // 16896
#define WCUT 1e-5f

typedef _Float16 half8  __attribute__((ext_vector_type(8)));
typedef _Float16 half2v __attribute__((ext_vector_type(2)));
typedef float f32x4 __attribute__((ext_vector_type(4)));

__device__ __forceinline__ void glds16(const _Float16* g, const _Float16* l){
    __builtin_amdgcn_global_load_lds(
        (const __attribute__((address_space(1))) void*)g,
        (__attribute__((address_space(3))) void*)l, 16, 0, 0);
}

// ---------------- fused prep: zero | wsplit x3 | bn_prep ----------------

__device__ __forceinline__ void wsplit_body(const float* __restrict__ w,
                                            _Float16* __restrict__ wh,
                                            _Float16* __restrict__ wl,
                                            int idx, int CO, int CI, int KK){
    if (idx >= CO*CI*KK) return;
    int co  = idx/(CI*KK);
    int r   = idx - co*CI*KK;
    int ci  = r/KK;
    int tap = r - ci*KK;
    float v = w[idx];
    _Float16 h = (_Float16)v;
    size_t o = ((size_t)tap*CO + co)*CI + ci;
    wh[o] = h; wl[o] = (_Float16)(v - (float)h);
}

__global__ void prep_kernel(int* __restrict__ zp, int nz,
                            const float* __restrict__ w1, _Float16* wh1, _Float16* wl1,
                            const float* __restrict__ w2, _Float16* wh2, _Float16* wl2,
                            const float* __restrict__ w3, _Float16* wh3, _Float16* wl3,
                            const float* __restrict__ c1b, const float* __restrict__ g1,
                            const float* __restrict__ bb1, const float* __restrict__ m1,
                            const float* __restrict__ v1,
                            const float* __restrict__ c2b, const float* __restrict__ g2,
                            const float* __restrict__ bb2, const float* __restrict__ m2,
                            const float* __restrict__ v2,
                            float* __restrict__ s1, float* __restrict__ t1,
                            float* __restrict__ s2, float* __restrict__ t2){
    int b = blockIdx.x, t = threadIdx.x;
    if (b < 129){
        int i = b*256 + t;
        if (i < nz) zp[i] = 0;
    } else if (b < 129 + 2304){
        wsplit_body(w1, wh1, wl1, (b-129)*256 + t, 256, 256, 9);
    } else if (b < 129 + 4608){
        wsplit_body(w2, wh2, wl2, (b-2433)*256 + t, 256, 256, 9);
    } else if (b < 129 + 4736){
        wsplit_body(w3, wh3, wl3, (b-4737)*256 + t, 128, 256, 1);
    } else {
        int c = t;
        float i1 = g1[c]/sqrtf(v1[c]+1e-3f);
        s1[c] = i1; t1[c] = (c1b[c]-m1[c])*i1 + bb1[c];
        float i2 = g2[c]/sqrtf(v2[c]+1e-3f);
        s2[c] = i2; t2[c] = (c2b[c]-m2[c])*i2 + bb2[c];
    }
}

// imgf [img][ci=256][pix] fp32 -> pixel-major fp16 hi/lo [img*HW+pix][256]
__global__ void tsplit(const float* __restrict__ imgf,
                       _Float16* __restrict__ inH, _Float16* __restrict__ inL){
    __shared__ float tile[32][33];
    int img = blockIdx.z;
    int p0 = blockIdx.x*32, c0 = blockIdx.y*32;
    int tx = threadIdx.x & 31, ty = threadIdx.x >> 5;
#pragma unroll
    for (int k = 0; k < 4; ++k)
        tile[ty + 8*k][tx] = imgf[((size_t)(img*256 + c0 + ty + 8*k))*HW + p0 + tx];
    __syncthreads();
#pragma unroll
    for (int k = 0; k < 4; ++k){
        int pr = ty + 8*k, cc = tx;
        float v = tile[cc][pr];
        _Float16 h = (_Float16)v;
        size_t o = ((size_t)(img*HW + p0 + pr))*256 + c0 + cc;
        inH[o] = h; inL[o] = (_Float16)(v - (float)h);
    }
}

// ---------------- depth distribution (recomputed) + histogram/fill --------

struct DepthCtx { float metric, inv, mx, rs; };

__device__ __forceinline__ DepthCtx depth_ctx(float relv, float lsc, float shf, float lsg){
    DepthCtx c;
    float scale = expf(lsc);
    float sig   = fminf(fmaxf(expf(lsg), 0.1f), 20.f);
    c.inv = 1.f/sig;
    c.metric = fminf(fmaxf(scale*relv + shf, 0.5f), 150.f);
    float nb = fminf(fmaxf(rintf(c.metric), 1.f), 59.f);
    c.mx = -fabsf(c.metric - nb)*c.inv;
    float sum = 0.f;
    for (int d = 0; d < DD; ++d)
        sum += expf(-fabsf(c.metric - (float)(d+1))*c.inv - c.mx);
    c.rs = 1.f/sum;
    return c;
}

__global__ void count_kernel(const float* __restrict__ rel, const int* __restrict__ vids,
                             const float* __restrict__ lsc, const float* __restrict__ shf,
                             const float* __restrict__ lsg, int* __restrict__ counts){
    int g = blockIdx.x*256 + threadIdx.x;
    if (g >= NPIX) return;
    int bn = g/HW, p = g - bn*HW;
    DepthCtx c = depth_ctx(rel[g], lsc[0], shf[0], lsg[0]);
    for (int d = 0; d < DD; ++d){
        float w = expf(-fabsf(c.metric - (float)(d+1))*c.inv - c.mx)*c.rs;
        if (w >= WCUT) atomicAdd(&counts[vids[(bn*DD + d)*HW + p]], 1);
    }
}

__global__ void scan_kernel(const int* __restrict__ counts, int* __restrict__ offsets){
    __shared__ int part[1024];
    int t = threadIdx.x;
    int base = t*16;
    int s = 0;
    for (int i = 0; i < 16; ++i) s += counts[base+i];
    part[t] = s;
    __syncthreads();
    for (int off = 1; off < 1024; off <<= 1){
        int v = (t >= off) ? part[t-off] : 0;
        __syncthreads();
        part[t] += v;
        __syncthreads();
    }
    int run = (t == 0) ? 0 : part[t-1];
    for (int i = 0; i < 16; ++i){
        offsets[base+i] = run;
        run += counts[base+i];
    }
}

__global__ void fill_kernel(const float* __restrict__ rel, const int* __restrict__ vids,
                            const float* __restrict__ lsc, const float* __restrict__ shf,
                            const float* __restrict__ lsg,
                            const int* __restrict__ offsets, int* __restrict__ cursor,
                            int2* __restrict__ records){
    int g = blockIdx.x*256 + threadIdx.x;
    if (g >= NPIX) return;
    int bn = g/HW, p = g - bn*HW;
    DepthCtx c = depth_ctx(rel[g], lsc[0], shf[0], lsg[0]);
    for (int d = 0; d < DD; ++d){
        float w = expf(-fabsf(c.metric - (float)(d+1))*c.inv - c.mx)*c.rs;
        if (w >= WCUT){
            int v = vids[(bn*DD + d)*HW + p];
            int pos = atomicAdd(&cursor[v], 1);
            records[offsets[v] + pos] = make_int2(g, __float_as_int(w));
        }
    }
}

// ---------------- MFMA conv v2: A direct->VGPR, B dbuf LDS, counted vmcnt --
// tile 64 px x 128 co, 256 thr = 4 waves (2x2), wave tile 32x64, BK=64.
// LDS 64KB: [buf:2][Bh|Bl][128 rows][64 k] swizzled slot = row*8 + (oct ^ (row&7))
template<int TAPS, bool BN_RELU, bool F16OUT, int COT>
__global__ __launch_bounds__(256,2) void conv_mfma(
    const _Float16* __restrict__ inH, const _Float16* __restrict__ inL,
    const _Float16* __restrict__ wHp, const _Float16* __restrict__ wLp,
    const float* __restrict__ scale, const float* __restrict__ bias,
    _Float16* __restrict__ outH, _Float16* __restrict__ outL,
    const _Float16* __restrict__ zp)
{
    __shared__ __align__(16) _Float16 lds[32768];

    const int t    = threadIdx.x;
    const int wave = t >> 6;
    const int lane = t & 63;
    const int g    = lane >> 4;
    const int l15  = lane & 15;
    const int wr   = wave >> 1, wc = wave & 1;
    const int g0   = blockIdx.x*64;          // 2816%64==0: tiles never cross images
    const int img  = g0/HW;
    const int pbase= g0 - img*HW;
    const int n0   = blockIdx.y*128;
    const int imgbase = img*HW;
    const int NK   = TAPS*4;

    int bOff[4], bLo[4];
#pragma unroll
    for (int i = 0; i < 4; ++i){
        int s = wave*256 + i*64 + lane;
        int row = s >> 3;
        bOff[i] = (n0 + row)*256 + ((s & 7) ^ (row & 7))*8;
        bLo[i]  = (wave*256 + i*64)*8;       // wave-uniform dest base (HW adds lane*16B)
    }
    int py[2], px[2];
#pragma unroll
    for (int f = 0; f < 2; ++f){
        int p = pbase + wr*32 + f*16 + l15;
        py[f] = p/88; px[f] = p - py[f]*88;
    }
    int brow[4];
#pragma unroll
    for (int f = 0; f < 4; ++f) brow[f] = wc*64 + f*16 + l15;

    f32x4 acc[2][4];
#pragma unroll
    for (int i = 0; i < 2; ++i)
#pragma unroll
        for (int j = 0; j < 4; ++j) acc[i][j] = (f32x4){0.f,0.f,0.f,0.f};

    struct AF { half8 h[2][2]; half8 l[2][2]; };   // [f][ks], static-indexed only
    AF A0, A1;

    auto stageB = [&](int kk, int buf){
        int tap = kk >> 2, ci0 = (kk & 3) << 6;
        const _Float16* bH = wHp + (size_t)tap*COT*256 + ci0;
        const _Float16* bL = wLp + (size_t)tap*COT*256 + ci0;
#pragma unroll
        for (int i = 0; i < 4; ++i){
            glds16(bH + bOff[i], lds + buf*16384 + bLo[i]);
            glds16(bL + bOff[i], lds + buf*16384 + 8192 + bLo[i]);
        }
    };
    auto loadA = [&](int kk, AF& A){
        int tap = kk >> 2, ci0 = (kk & 3) << 6;
        int dy = (TAPS == 9) ? tap/3 - 1 : 0;
        int dx = (TAPS == 9) ? tap - (tap/3)*3 - 1 : 0;
#pragma unroll
        for (int f = 0; f < 2; ++f){
            int yy = py[f] + dy, xx = px[f] + dx;
            bool valid = ((unsigned)yy < 32u) && ((unsigned)xx < 88u);
            int base = (imgbase + yy*88 + xx)*256 + ci0 + g*8;
            const _Float16* pH = valid ? inH + base : zp;
            const _Float16* pL = valid ? inL + base : zp;
            A.h[f][0] = *(const half8*)(pH);
            A.h[f][1] = *(const half8*)(pH + 32);
            A.l[f][0] = *(const half8*)(pL);
            A.l[f][1] = *(const half8*)(pL + 32);
        }
    };
    auto compute = [&](int buf, AF& A){
#pragma unroll
        for (int ks = 0; ks < 2; ++ks){
            half8 bh[4], bl[4];
#pragma unroll
            for (int f = 0; f < 4; ++f){
                int eb = brow[f]*64 + (((ks*4 + g) ^ (brow[f] & 7))*8);
                bh[f] = *(const half8*)(lds + buf*16384 + eb);
                bl[f] = *(const half8*)(lds + buf*16384 + 8192 + eb);
            }
#pragma unroll
            for (int mi = 0; mi < 2; ++mi)
#pragma unroll
            for (int ni = 0; ni < 4; ++ni){
                acc[mi][ni] = __builtin_amdgcn_mfma_f32_16x16x32_f16(A.h[mi][ks], bh[ni], acc[mi][ni], 0,0,0);
                acc[mi][ni] = __builtin_amdgcn_mfma_f32_16x16x32_f16(A.h[mi][ks], bl[ni], acc[mi][ni], 0,0,0);
                acc[mi][ni] = __builtin_amdgcn_mfma_f32_16x16x32_f16(A.l[mi][ks], bh[ni], acc[mi][ni], 0,0,0);
            }
        }
    };

    // prologue: two K-steps in flight
    stageB(0, 0); loadA(0, A0);
    stageB(1, 1); loadA(1, A1);

    for (int kk2 = 0; kk2 < NK; kk2 += 2){
        // even step: compute buf0 / A0 ; keep B(kk2+1),A(kk2+1) in flight
        asm volatile("s_waitcnt vmcnt(16)" ::: "memory");
        __builtin_amdgcn_s_barrier();
        compute(0, A0);
        asm volatile("s_waitcnt lgkmcnt(0)" ::: "memory");
        __builtin_amdgcn_s_barrier();
        if (kk2 + 2 < NK){ stageB(kk2 + 2, 0); loadA(kk2 + 2, A0); }
        // odd step
        if (kk2 + 2 < NK){ asm volatile("s_waitcnt vmcnt(16)" ::: "memory"); }
        else             { asm volatile("s_waitcnt vmcnt(0)"  ::: "memory"); }
        __builtin_amdgcn_s_barrier();
        compute(1, A1);
        asm volatile("s_waitcnt lgkmcnt(0)" ::: "memory");
        __builtin_amdgcn_s_barrier();
        if (kk2 + 3 < NK){ stageB(kk2 + 3, 1); loadA(kk2 + 3, A1); }
    }

    // epilogue: C/D col(l15)=co, row=(lane>>4)*4+r = pixel
#pragma unroll
    for (int ni = 0; ni < 4; ++ni){
        int co = n0 + wc*64 + ni*16 + l15;
        float sc = BN_RELU ? scale[co] : 0.f;
        float bi = bias[co];
#pragma unroll
        for (int mi = 0; mi < 2; ++mi){
            f32x4 v = acc[mi][ni];
            int rb = g0 + wr*32 + mi*16 + g*4;
#pragma unroll
            for (int r = 0; r < 4; ++r){
                float y;
                if (BN_RELU) y = fmaxf(fmaf(v[r], sc, bi), 0.f);
                else         y = v[r] + bi;
                size_t o = (size_t)(rb + r)*COT + co;
                if constexpr (F16OUT){
                    outH[o] = (_Float16)y;
                } else {
                    _Float16 h = (_Float16)y;
                    outH[o] = h;
                    outL[o] = (_Float16)(y - (float)h);
                }
            }
        }
    }
}

// ---------------- atomic-free splat: gather per voxel (fp16 feat) ----------
// one wave per voxel, lane = 2 channels, 8-deep unrolled for MLP
__global__ __launch_bounds__(256,8) void gather_kernel(
    const int2* __restrict__ records, const int* __restrict__ offsets,
    const int* __restrict__ counts, const _Float16* __restrict__ feat16,
    float* __restrict__ bev_t){
    int v    = blockIdx.x*4 + (threadIdx.x >> 6);
    int lane = threadIdx.x & 63;
    int off = offsets[v], n = counts[v];
    float a0 = 0.f, a1 = 0.f;
    int i = 0;
    for (; i + 8 <= n; i += 8){
        int2 r[8];
#pragma unroll
        for (int j = 0; j < 8; ++j) r[j] = records[off+i+j];
        half2v f[8];
#pragma unroll
        for (int j = 0; j < 8; ++j)
            f[j] = *(const half2v*)(feat16 + (size_t)r[j].x*COUT + lane*2);
#pragma unroll
        for (int j = 0; j < 8; ++j){
            float w = __int_as_float(r[j].y);
            a0 = fmaf(w, (float)f[j][0], a0);
            a1 = fmaf(w, (float)f[j][1], a1);
        }
    }
    for (; i < n; ++i){
        int2 r = records[off+i];
        half2v f = *(const half2v*)(feat16 + (size_t)r.x*COUT + lane*2);
        float w = __int_as_float(r.y);
        a0 = fmaf(w, (float)f[0], a0); a1 = fmaf(w, (float)f[1], a1);
    }
    *(float2*)(bev_t + (size_t)v*COUT + lane*2) = make_float2(a0, a1);
}

// bev_t[v][c] -> out[c][v]
__global__ void transpose_out(const float* __restrict__ bev_t, float* __restrict__ out){
    __shared__ float tile[32][33];
    int v0 = blockIdx.x*32, c0 = blockIdx.y*32;
    int tx = threadIdx.x & 31, ty = threadIdx.x >> 5;
#pragma unroll
    for (int k = 0; k < 4; ++k)
        tile[ty + 8*k][tx] = bev_t[(size_t)(v0 + ty + 8*k)*COUT + c0 + tx];
    __syncthreads();
#pragma unroll
    for (int k = 0; k < 4; ++k)
        out[(size_t)(c0 + ty + 8*k)*NV + v0 + tx] = tile[tx][ty + 8*k];
}

// ---------------- launch ----------------

extern "C" void kernel_launch(void* const* d_in, const int* in_sizes, int n_in,
                              void* d_out, int out_size, void* d_ws, size_t ws_size,
                              hipStream_t stream){
    const float* rel  = (const float*)d_in[0];
    const float* imgf = (const float*)d_in[1];
    const int*   vids = (const int*)d_in[2];
    const float* lsc  = (const float*)d_in[3];
    const float* shf  = (const float*)d_in[4];
    const float* lsg  = (const float*)d_in[5];
    const float* w1   = (const float*)d_in[6];
    const float* b1   = (const float*)d_in[7];
    const float* g1   = (const float*)d_in[8];
    const float* bb1  = (const float*)d_in[9];
    const float* m1   = (const float*)d_in[10];
    const float* v1   = (const float*)d_in[11];
    const float* w2   = (const float*)d_in[12];
    const float* b2   = (const float*)d_in[13];
    const float* g2   = (const float*)d_in[14];
    const float* bb2  = (const float*)d_in[15];
    const float* m2   = (const float*)d_in[16];
    const float* v2   = (const float*)d_in[17];
    const float* w3   = (const float*)d_in[18];
    const float* b3   = (const float*)d_in[19];

    char* ws = (char*)d_ws;
    size_t o = 0;
    auto alloc = [&](size_t bytes)->char*{
        char* p = ws + o;
        o += (bytes + 255) & ~(size_t)255;
        return p;
    };
    int* counts  = (int*)alloc((size_t)(2*NV + 64)*4);   // counts | cursor | zpad(256B)
    int* cursor  = counts + NV;
    const _Float16* zpad16 = (const _Float16*)(counts + 2*NV);
    int* offsets = (int*)alloc((size_t)NV*4);

    _Float16* wT1H = (_Float16*)alloc((size_t)9*256*256*2);
    _Float16* wT1L = (_Float16*)alloc((size_t)9*256*256*2);
    _Float16* wT2H = (_Float16*)alloc((size_t)9*256*256*2);
    _Float16* wT2L = (_Float16*)alloc((size_t)9*256*256*2);
    _Float16* wT3H = (_Float16*)alloc((size_t)128*256*2);
    _Float16* wT3L = (_Float16*)alloc((size_t)128*256*2);
    float* s1 = (float*)alloc(256*4);
    float* t1 = (float*)alloc(256*4);
    float* s2 = (float*)alloc(256*4);
    float* t2 = (float*)alloc(256*4);

    _Float16* in0H = (_Float16*)alloc((size_t)NPIX*256*2);   // 8.65 MB
    _Float16* in0L = (_Float16*)alloc((size_t)NPIX*256*2);
    _Float16* h1H  = (_Float16*)alloc((size_t)NPIX*256*2);
    _Float16* h1L  = (_Float16*)alloc((size_t)NPIX*256*2);
    _Float16* feat16 = (_Float16*)alloc((size_t)NPIX*COUT*2);  // 4.3 MB
    float* bev_t   = (float*)alloc((size_t)NV*COUT*4);          // 8 MB
    // aliases: h2 planes reuse in0 (dead after conv1); records reuse h1L (dead after conv3)
    _Float16* h2H = in0H;
    _Float16* h2L = in0L;
    int2* records = (int2*)h1L;   // <= 8 MB needed, 8.65 MB available

    prep_kernel<<<4866,256,0,stream>>>(counts, 2*NV + 64,
        w1, wT1H, wT1L, w2, wT2H, wT2L, w3, wT3H, wT3L,
        b1,g1,bb1,m1,v1, b2,g2,bb2,m2,v2, s1,t1,s2,t2);
    tsplit<<<dim3(88,8,6),256,0,stream>>>(imgf, in0H, in0L);

    conv_mfma<9,true ,false,256><<<dim3(264,2),256,0,stream>>>(
        in0H, in0L, wT1H, wT1L, s1, t1, h1H, h1L, zpad16);
    conv_mfma<9,true ,false,256><<<dim3(264,2),256,0,stream>>>(
        h1H, h1L, wT2H, wT2L, s2, t2, h2H, h2L, zpad16);
    conv_mfma<1,false,true ,128><<<dim3(264,1),256,0,stream>>>(
        h2H, h2L, wT3H, wT3L, s1, b3, feat16, nullptr, zpad16);

    count_kernel<<<66,256,0,stream>>>(rel, vids, lsc, shf, lsg, counts);
    scan_kernel<<<1,1024,0,stream>>>(counts, offsets);
    fill_kernel<<<66,256,0,stream>>>(rel, vids, lsc, shf, lsg, offsets, cursor, records);

    gather_kernel<<<4096,256,0,stream>>>(records, offsets, counts, feat16, bev_t);
    transpose_out<<<dim3(512,4),256,0,stream>>>(bev_t, (float*)d_out);
}